// Round 1
// 286.631 us; speedup vs baseline: 1.1349x; 1.1349x over previous
//
#include <hip/hip_runtime.h>
#include <stdint.h>

#define Bb 64
#define Hh 128
#define Ww 128
#define Cc 21
#define Pp 49152          // NUM_SAMPLED
#define Kk 36864          // NUM_UNCERTAIN
#define NR 12288          // NUM_RANDOM

#define BINS 2048         // 11-bit digits; pass shifts 16/27/38 (bits >=47 are 0)
#define TILE 4096         // elements per sort tile
#define TILES 12          // Pp / TILE
#define NBLK (Bb * TILES) // 768 sample/scatter blocks

typedef uint32_t u32;
typedef uint64_t u64;
typedef unsigned short u16;

// XCD-affine decode: all TILES blocks of segment s have blk%8 == s%8, so the
// round-robin block->XCD dispatch keeps a segment's r/w window in ONE XCD's
// L2. Performance heuristic only; correctness never depends on placement.
#define DECODE_ST const int s = blk & 63; const int t = blk >> 6;

// 11-bit ballot digit-match: mask of lanes in this wave holding digit d.
__device__ __forceinline__ u64 match11(u32 d) {
    u64 m = ~0ull;
    #pragma unroll
    for (int bit = 0; bit < 11; ++bit) {
        u64 bl = __ballot((d >> bit) & 1u);
        m &= ((d >> bit) & 1u) ? bl : ~bl;
    }
    return m;
}

// ---------------------------------------------------------------------------
// Kernel 0: compact channel-0 plane: planes[b][h][w] = logits[b][h][w][0].
// ---------------------------------------------------------------------------
__global__ __launch_bounds__(256) void extract_kernel(const float* __restrict__ logits,
                                                      float* __restrict__ planes) {
    int gid = blockIdx.x * blockDim.x + threadIdx.x;   // [0, B*H*W)
    planes[gid] = logits[(size_t)gid * Cc];
}

// ---------------------------------------------------------------------------
// Kernel 1: bilinear sample (64 KB plane staged in LDS), build sortable key,
// fused pass-0 per-tile histogram. key = fp32 bits of |interp| (order-
// isomorphic for non-negative floats); element = (key << 16) | idx.
// Hist table layout is tile-major [s][t][d] so scatter's prologue reads and
// these writes are lane-consecutive (coalesced).
// fp contract OFF: the sort permutation feeds the output directly — bit-exact
// numpy arithmetic required (one rank flip = O(1) absmax error).
// ---------------------------------------------------------------------------
__global__ __launch_bounds__(256) void sample_key_kernel(const float* __restrict__ planes,
                                                         const float2* __restrict__ coords,
                                                         u64* __restrict__ keys,
                                                         u32* __restrict__ hist) {
#pragma clang fp contract(off)
    __shared__ float pl[Hh * Ww];      // 64 KB
    __shared__ u32 h[BINS];            // 8 KB
    const int tid = threadIdx.x;
    const int blk = blockIdx.x;
    DECODE_ST

    for (int i = tid; i < BINS; i += 256) h[i] = 0;
    const float4* p4 = (const float4*)(planes + s * (Hh * Ww));
    float4* l4 = (float4*)pl;
    #pragma unroll
    for (int i = 0; i < 16; ++i) l4[i * 256 + tid] = p4[i * 256 + tid];
    __syncthreads();

    #pragma unroll 4
    for (int i = 0; i < 16; ++i) {
        int idx = t * TILE + i * 256 + tid;            // point index within segment
        int gid = s * Pp + idx;
        float2 c = coords[gid];
        float xf = c.x * 127.0f;                       // coords[...,0] -> H axis
        float yf = c.y * 127.0f;                       // coords[...,1] -> W axis
        float x0 = floorf(xf), x1 = ceilf(xf);
        float y0 = floorf(yf), y1 = ceilf(yf);
        float mux = xf - x0;
        float muy = yf - y0;
        int x0i = (int)x0, x1i = (int)x1, y0i = (int)y0, y1i = (int)y1;
        float p1 = pl[x0i * Ww + y0i];
        float p2 = pl[x1i * Ww + y0i];
        float p3 = pl[x0i * Ww + y1i];
        float p4v = pl[x1i * Ww + y1i];
        float p12 = p1 * (1.0f - mux) + p2 * mux;
        float p34 = p3 * (1.0f - mux) + p4v * mux;
        float r   = p12 * (1.0f - muy) + p34 * muy;
        u32 kb = __float_as_uint(r) & 0x7fffffffu;     // |r| bits
        keys[gid] = ((u64)kb << 16) | (u32)idx;
        atomicAdd(&h[kb & (BINS - 1)], 1u);            // pass-0 digit (uniform)
    }
    __syncthreads();
    const size_t hbase = ((size_t)s * TILES + t) * BINS;
    #pragma unroll
    for (int j = 0; j < 8; ++j) {
        int d = j * 256 + tid;
        hist[hbase + d] = h[d];
    }
}

// ---------------------------------------------------------------------------
// Kernel 2 (passes 1,2): per-tile histogram via per-wave privatized LDS
// counters + plain atomicAdd (no ballots: even the skewed exponent digit has
// only ~3-8-way same-address collisions, far cheaper than 22 VALU ops/elem).
// Output layout [s][t][d] (tile-major, coalesced).
// ---------------------------------------------------------------------------
__global__ __launch_bounds__(256) void hist_kernel(const u64* __restrict__ in,
                                                   u32* __restrict__ hist, int shift) {
    __shared__ u32 h[4][BINS];         // 32 KB, one table per wave
    const int tid = threadIdx.x;
    const int w = tid >> 6;
    const int blk = blockIdx.x;
    DECODE_ST
    for (int i = tid; i < 4 * BINS; i += 256) ((u32*)h)[i] = 0;
    __syncthreads();
    const u64* src = in + (size_t)s * Pp + t * TILE;
    #pragma unroll 4
    for (int i = 0; i < 16; ++i) {
        u64 v = src[i * 256 + tid];
        u32 d = (u32)(v >> shift) & (BINS - 1);
        atomicAdd(&h[w][d], 1u);
    }
    __syncthreads();
    const size_t hbase = ((size_t)s * TILES + t) * BINS;
    #pragma unroll
    for (int j = 0; j < 8; ++j) {
        int d = j * 256 + tid;
        hist[hbase + d] = h[0][d] + h[1][d] + h[2][d] + h[3][d];
    }
}

// ---------------------------------------------------------------------------
// Kernel 3: stable scatter. NEW: no separate scan kernel — each block derives
// its global offsets from the RAW per-tile hist table in a prologue:
//   off[s][d][t] = sum_{d'<d} segtot[d'] + sum_{t'<t} cnt[d][t']
// The per-segment table (96 KB) is L2-hot (12 blocks/segment re-read it,
// XCD-affine), prologue loads are coalesced (d = j*256+tid), and the global
// digit-exclusive scan is packed into the EXISTING local block-scan as the
// high word of a u64 (both fields < 2^32, no cross-carry: local<=4096,
// global<=49152). Scan scratch lives in el[] (dead until phase B).
// match11 computed ONCE per element (cached digit/rank/count/leader flags
// reused in phase B). NO fused global-atomic histogram (round-5 lesson:
// 3.1M scattered global atomics cost ~240 µs, 50x the hist kernel).
// Final pass: emit out[s][g] = coords[s][idx] for g < K, plus fused
// extra_random copy into rows [K, P).
// ---------------------------------------------------------------------------
__global__ __launch_bounds__(256) void scatter_kernel(const u64* __restrict__ in,
                                                      u64* __restrict__ out_keys,
                                                      const u32* __restrict__ hist,
                                                      int shift, int final_pass,
                                                      const float2* __restrict__ coords,
                                                      const float2* __restrict__ extra,
                                                      float2* __restrict__ out) {
    __shared__ u64 el[TILE];           // 32 KB (scan scratch before phase B)
    __shared__ u16 wh[BINS * 4];       // 16 KB  [digit][wave] counts -> local bases
    __shared__ u16 dl[BINS];           // 4 KB   delta[d] (mod 2^16)
    __shared__ u64 aux[4];
    const int tid = threadIdx.x;
    const int lane = tid & 63;
    const int w = tid >> 6;
    const int blk = blockIdx.x;
    DECODE_ST
    const u64* src = in + (size_t)s * Pp + t * TILE;

    for (int i = tid; i < BINS * 4; i += 256) wh[i] = 0;
    u64 v[16];
    #pragma unroll
    for (int i = 0; i < 16; ++i) v[i] = src[w * 1024 + i * 64 + lane];

    // prologue: segment totals + prior-tile prefixes per digit, into el scratch
    {
        u32* sc1 = (u32*)el;                 // [BINS] segment totals
        u32* sc2 = sc1 + BINS;               // [BINS] sum over tiles < t
        const u32* hb = hist + (size_t)s * (TILES * BINS);
        #pragma unroll
        for (int j = 0; j < 8; ++j) {
            int d = j * 256 + tid;
            u32 tot = 0, pre = 0;
            #pragma unroll
            for (int tt = 0; tt < TILES; ++tt) {
                u32 c = hb[tt * BINS + d];   // coalesced, L2-hot
                tot += c;
                pre += (tt < t) ? c : 0;
            }
            sc1[d] = tot;
            sc2[d] = pre;
        }
    }
    __syncthreads();

    // phase A: per-wave digit histogram; cache match results for phase B.
    // pk[i] = before | (cnt << 8) | (leader << 16)
    const u64 ltmask = (1ull << lane) - 1ull;
    u32 dg[16], pk[16];
    volatile u16* vwh = wh;
    #pragma unroll 2
    for (int i = 0; i < 16; ++i) {
        u32 d = (u32)(v[i] >> shift) & (BINS - 1);
        u64 m = match11(d);
        u32 before = (u32)__popcll(m & ltmask);
        u32 cnt = (u32)__popcll(m);
        bool lead = (lane == __ffsll((unsigned long long)m) - 1);
        dg[i] = d;
        pk[i] = before | (cnt << 8) | (lead ? 0x10000u : 0u);
        if (lead) {
            u32 p = d * 4 + w;
            vwh[p] = (u16)(vwh[p] + cnt);
        }
    }
    __syncthreads();

    // scan: thread owns 8 digits; dual block-scan packed in u64:
    // low word = local (this-tile) element count, high word = segment count.
    const u32* sc1 = (const u32*)el;
    const u32* sc2 = sc1 + BINS;
    const int d0 = tid * 8;
    u32 dtot[8], gtot[8], gpre[8];
    u32 t8l = 0, t8g = 0;
    #pragma unroll
    for (int j = 0; j < 8; ++j) {
        int d = d0 + j;
        u32 c = (u32)wh[d * 4 + 0] + wh[d * 4 + 1] + wh[d * 4 + 2] + wh[d * 4 + 3];
        dtot[j] = c;
        t8l += c;
        gtot[j] = sc1[d];
        gpre[j] = sc2[d];
        t8g += gtot[j];
    }
    u64 own = ((u64)t8g << 32) | t8l;
    u64 sc = own;
    for (int o = 1; o < 64; o <<= 1) {
        u64 n = __shfl_up((unsigned long long)sc, o);
        if (lane >= o) sc += n;
    }
    if (lane == 63) aux[w] = sc;
    __syncthreads();
    if (tid == 0) {
        u64 run = 0;
        for (int i = 0; i < 4; ++i) { u64 x = aux[i]; aux[i] = run; run += x; }
    }
    __syncthreads();
    u64 excl = sc - own + aux[w];
    u32 run_l = (u32)excl;             // local exclusive base for thread's digits
    u32 run_g = (u32)(excl >> 32);     // segment digit-exclusive base
    #pragma unroll
    for (int j = 0; j < 8; ++j) {
        int d = d0 + j;
        u32 ls = run_l;                // local_start[d]
        u32 g = run_g + gpre[j];       // global offset off[s][d][t]
        dl[d] = (u16)(g - ls);
        u32 c0 = wh[d * 4 + 0], c1 = wh[d * 4 + 1], c2 = wh[d * 4 + 2];
        wh[d * 4 + 0] = (u16)ls;
        wh[d * 4 + 1] = (u16)(ls + c0);
        wh[d * 4 + 2] = (u16)(ls + c0 + c1);
        wh[d * 4 + 3] = (u16)(ls + c0 + c1 + c2);
        run_l += dtot[j];
        run_g += gtot[j];
    }
    __syncthreads();

    // phase B: stable scatter into LDS using cached ranks (no ballots here).
    for (int i = 0; i < 16; ++i) {
        u32 d = dg[i];
        u32 before = pk[i] & 0xffu;
        u32 base = vwh[d * 4 + w];
        el[base + before] = v[i];
        if (pk[i] & 0x10000u)
            vwh[d * 4 + w] = (u16)(base + ((pk[i] >> 8) & 0xffu));
    }
    __syncthreads();

    // phase C: linear read-back, run-contiguous global write
    if (!final_pass) {
        u64* dst = out_keys + (size_t)s * Pp;
        for (int i = 0; i < 16; ++i) {
            int pos = i * 256 + tid;
            u64 e = el[pos];
            u32 d = (u32)(e >> shift) & (BINS - 1);
            u32 g = (u32)(u16)(pos + dl[d]);
            dst[g] = e;
        }
    } else {
        const float2* cseg = coords + (size_t)s * Pp;
        float2* oseg = out + (size_t)s * Pp;
        for (int i = 0; i < 16; ++i) {
            int pos = i * 256 + tid;
            u64 e = el[pos];
            u32 d = (u32)(e >> shift) & (BINS - 1);
            u32 g = (u32)(u16)(pos + dl[d]);
            if (g < Kk) {
                u32 idx = (u32)e & 0xffffu;
                oseg[g] = cseg[idx];
            }
        }
        // fused extra_random copy: rows [K, P) of this segment, 1024 per tile
        const float2* eseg = extra + (size_t)s * NR;
        float2* xseg = out + (size_t)s * Pp + Kk;
        #pragma unroll
        for (int i = 0; i < 4; ++i) {
            int p = t * 1024 + i * 256 + tid;
            xseg[p] = eseg[p];
        }
    }
}

extern "C" void kernel_launch(void* const* d_in, const int* in_sizes, int n_in,
                              void* d_out, int out_size, void* d_ws, size_t ws_size,
                              hipStream_t stream) {
    const float*  logits = (const float*)d_in[0];   // (B,H,W,C) fp32
    const float2* coords = (const float2*)d_in[1];  // (B,P,2)  fp32
    const float2* extra  = (const float2*)d_in[2];  // (B,NR,2) fp32
    float2* out = (float2*)d_out;

    u64* buf0 = (u64*)d_ws;                          // 25.2 MB
    u64* buf1 = buf0 + (size_t)Bb * Pp;              // 25.2 MB (ping-pong)
    float* planes = (float*)buf1;                    // 4 MB; dead before pass-0 scatter writes buf1
    u32* histA = (u32*)d_out;                        // 6.3 MB scratch (passes 0,1); d_out untouched until final pass
    u32* histB = (u32*)buf1;                         // pass-2 raw hist in buf1 (dead then; final scatter reads buf0)

    extract_kernel<<<(Bb * Hh * Ww) / 256, 256, 0, stream>>>(logits, planes);
    sample_key_kernel<<<NBLK, 256, 0, stream>>>(planes, coords, buf0, histA);

    // pass 0: bits [16,27)  buf0 -> buf1  (offsets derived in-kernel from histA)
    scatter_kernel<<<NBLK, 256, 0, stream>>>(buf0, buf1, histA, 16, 0, nullptr, nullptr, nullptr);
    // pass 1: bits [27,38)  buf1 -> buf0
    hist_kernel<<<NBLK, 256, 0, stream>>>(buf1, histA, 27);
    scatter_kernel<<<NBLK, 256, 0, stream>>>(buf1, buf0, histA, 27, 0, nullptr, nullptr, nullptr);
    // pass 2: bits [38,47)  buf0 -> out (fused gather+emit+extra copy)
    hist_kernel<<<NBLK, 256, 0, stream>>>(buf0, histB, 38);
    scatter_kernel<<<NBLK, 256, 0, stream>>>(buf0, nullptr, histB, 38, 1, coords, extra, out);
}